// Round 12
// baseline (363.866 us; speedup 1.0000x reference)
//
#include <hip/hip_runtime.h>
#include <hip/hip_bf16.h>
#include <math.h>

// Problem constants (from reference): H=4 heads, F=64 per-head, H*F=256.
#define HF    256
#define HEADS 4
#define FD    64
#define NEG_SLOPE 0.2f

typedef __attribute__((ext_vector_type(8))) short short8;
typedef __attribute__((ext_vector_type(4))) float f32x4;

__device__ __forceinline__ float wave_sum(float v) {
  #pragma unroll
  for (int off = 32; off; off >>= 1) v += __shfl_xor(v, off);
  return v;
}

// f32 -> bf16 round-to-nearest-even (raw bits).
__device__ __forceinline__ unsigned short f2bf(float f) {
  unsigned u = __float_as_uint(f);
  u += 0x7FFFu + ((u >> 16) & 1u);
  return (unsigned short)(u >> 16);
}
__device__ __forceinline__ float bf2f(unsigned short u) {
  return __uint_as_float((unsigned)u << 16);
}

// async global->LDS, 16 B per lane (wave-uniform LDS base + lane*16).
__device__ __forceinline__ void gload_lds16(const void* g, void* l) {
  __builtin_amdgcn_global_load_lds((const unsigned int*)g, (unsigned int*)l,
                                   16, 0, 0);
}

// ---------------------------------------------------------------------------
// bf16 MFMA GEMM: C[Mpad x 512] = A[Mpad x K] @ B[K x 512], B given
// pre-transposed as BT[512 x K]. Output cols 0..255 -> featbf, 256..511 ->
// resbf (both bf16). For the feat half, each wave owns exactly one head's 64
// columns -> el/er computed in-register (16-lane shfl reduce over f32 acc).
// 128x128 tile, 4 waves (2x2), 4x4 fragments of 16x16x32, BK=32 (m97-lite).
// ---------------------------------------------------------------------------
template<int K>
__global__ __launch_bounds__(256) void gemm_mfma(
    const unsigned short* __restrict__ A,   // [Mpad][K] bf16 bits
    const unsigned short* __restrict__ BT,  // [512][K]  bf16 bits
    const float* __restrict__ al, const float* __restrict__ ar,
    unsigned short* __restrict__ featbf, unsigned short* __restrict__ resbf,
    float* __restrict__ el, float* __restrict__ er, int M)
{
  __shared__ __align__(16) unsigned short As[128 * 32];
  __shared__ __align__(16) unsigned short Bs[128 * 32];
  const int t    = threadIdx.x;
  const int lane = t & 63, w = t >> 6;
  const int wr = w >> 1, wc = w & 1;
  const int l15 = lane & 15, lhi = lane >> 4;
  const int row0 = blockIdx.x * 128;
  const int n0b  = blockIdx.y;             // 0,1 -> feat; 2,3 -> res

  // staging chunks: 512 chunks of 16B per tile; chunk c: row=c>>2, col8=(c&3)*8
  const int c0 = w * 128 + lane;
  const int c1 = c0 + 64;
  const unsigned short* gA0 = A  + (size_t)(row0 + (c0 >> 2)) * K + (c0 & 3) * 8;
  const unsigned short* gA1 = A  + (size_t)(row0 + (c1 >> 2)) * K + (c1 & 3) * 8;
  const unsigned short* gB0 = BT + (size_t)(n0b * 128 + (c0 >> 2)) * K + (c0 & 3) * 8;
  const unsigned short* gB1 = BT + (size_t)(n0b * 128 + (c1 >> 2)) * K + (c1 & 3) * 8;
  unsigned short* lA0 = &As[w * 1024];
  unsigned short* lA1 = &As[w * 1024 + 512];
  unsigned short* lB0 = &Bs[w * 1024];
  unsigned short* lB1 = &Bs[w * 1024 + 512];

  f32x4 acc[4][4];
  #pragma unroll
  for (int i = 0; i < 4; ++i)
    #pragma unroll
    for (int j = 0; j < 4; ++j)
      acc[i][j] = (f32x4){0.f, 0.f, 0.f, 0.f};

  for (int k0 = 0; k0 < K; k0 += 32) {
    __syncthreads();                       // prev iter's ds_reads done
    gload_lds16(gA0 + k0, lA0);
    gload_lds16(gA1 + k0, lA1);
    gload_lds16(gB0 + k0, lB0);
    gload_lds16(gB1 + k0, lB1);
    __syncthreads();                       // drains vmcnt -> LDS tiles ready

    short8 a[4], b[4];
    #pragma unroll
    for (int im = 0; im < 4; ++im)
      a[im] = *(const short8*)&As[(wr * 64 + im * 16 + l15) * 32 + lhi * 8];
    #pragma unroll
    for (int jn = 0; jn < 4; ++jn)
      b[jn] = *(const short8*)&Bs[(wc * 64 + jn * 16 + l15) * 32 + lhi * 8];
    #pragma unroll
    for (int im = 0; im < 4; ++im)
      #pragma unroll
      for (int jn = 0; jn < 4; ++jn)
        acc[im][jn] = __builtin_amdgcn_mfma_f32_16x16x32_bf16(
            a[im], b[jn], acc[im][jn], 0, 0, 0);
  }

  // C/D layout: col = lane&15, row = (lane>>4)*4 + q   [m89/m91 verified]
  unsigned short* outp = (n0b < 2) ? featbf : resbf;
  const int colbase = (n0b & 1) * 128 + wc * 64;
  #pragma unroll
  for (int im = 0; im < 4; ++im) {
    const int rowb = row0 + wr * 64 + im * 16 + lhi * 4;
    #pragma unroll
    for (int q = 0; q < 4; ++q) {
      if (rowb + q < M) {
        unsigned short* rp = outp + (size_t)(rowb + q) * HF + colbase;
        #pragma unroll
        for (int jn = 0; jn < 4; ++jn)
          rp[jn * 16 + l15] = f2bf(acc[im][jn][q]);
      }
    }
  }

  // el/er for the feat half: wave (n0b,wc) owns head hd's full 64 columns.
  if (n0b < 2) {
    const int hd = n0b * 2 + wc;
    float alv[4], arv[4];
    #pragma unroll
    for (int jn = 0; jn < 4; ++jn) {
      alv[jn] = al[hd * FD + jn * 16 + l15];
      arv[jn] = ar[hd * FD + jn * 16 + l15];
    }
    #pragma unroll
    for (int im = 0; im < 4; ++im) {
      #pragma unroll
      for (int q = 0; q < 4; ++q) {
        float es = 0.f, rs = 0.f;
        #pragma unroll
        for (int jn = 0; jn < 4; ++jn) {
          es = fmaf(acc[im][jn][q], alv[jn], es);
          rs = fmaf(acc[im][jn][q], arv[jn], rs);
        }
        #pragma unroll
        for (int off = 1; off < 16; off <<= 1) {   // reduce across l15 group
          es += __shfl_xor(es, off);
          rs += __shfl_xor(rs, off);
        }
        const int row = row0 + wr * 64 + im * 16 + lhi * 4 + q;
        if (l15 == 0 && row < M) {
          el[row * HEADS + hd] = es;
          er[row * HEADS + hd] = rs;
        }
      }
    }
  }
}

// ---------------------------------------------------------------------------
// Fused conversions + ALL scratch init: x->bf16, BT1, BT2, counts=0,
// cursor=0, wsum=0, hmax=enc(-inf). One linear index space.
// ---------------------------------------------------------------------------
__global__ void k_cvt_init(
    const float* __restrict__ x,
    const float* __restrict__ W1, const float* __restrict__ Wres1,
    const float* __restrict__ W2, const float* __restrict__ Wres2,
    unsigned short* __restrict__ xbf, unsigned short* __restrict__ BT1,
    unsigned short* __restrict__ BT2, int* __restrict__ counts,
    int* __restrict__ cursor, float* __restrict__ wsum,
    unsigned* __restrict__ hmax, int n4, int N, int GFD)
{
  int i = blockIdx.x * 256 + threadIdx.x;
  if (i < n4) {
    float4 v = ((const float4*)x)[i];
    ushort4 o;
    o.x = f2bf(v.x); o.y = f2bf(v.y); o.z = f2bf(v.z); o.w = f2bf(v.w);
    ((ushort4*)xbf)[i] = o;
    return;
  }
  i -= n4;
  if (i < 512 * 64) {
    int j = i >> 6, k = i & 63;
    float v = (j < HF) ? W1[k * HF + j] : Wres1[k * HF + (j - HF)];
    BT1[i] = f2bf(v);
    return;
  }
  i -= 512 * 64;
  if (i < 512 * 256) {
    int j = i >> 8, k = i & 255;
    float v = (j < HF) ? W2[k * HF + j] : Wres2[k * HF + (j - HF)];
    BT2[i] = f2bf(v);
    return;
  }
  i -= 512 * 256;
  if (i < N) { counts[i] = 0; return; }
  i -= N;
  if (i < N) { cursor[i] = 0; return; }
  i -= N;
  if (i < GFD) { wsum[i] = 0.f; return; }
  i -= GFD;
  if (i < GFD) hmax[i] = 0x007FFFFFu;         // enc(-inf)
}

// ---------------------------------------------------------------------------
// CSR build: histogram -> 2-level exclusive scan -> scatter.
// ---------------------------------------------------------------------------
__global__ void k_hist(const int* __restrict__ dst, int* __restrict__ counts, int E) {
  int i = blockIdx.x * 256 + threadIdx.x;
  if (i < E) atomicAdd(&counts[dst[i]], 1);
}

__global__ __launch_bounds__(256) void k_scan1(
    const int* __restrict__ counts, int* __restrict__ offs,
    int* __restrict__ bsum, int n)
{
  __shared__ int lds[256];
  const int b = blockIdx.x, t = threadIdx.x;
  const int base = b * 1024 + t * 4;
  int v[4];
  #pragma unroll
  for (int i = 0; i < 4; ++i) { int idx = base + i; v[i] = (idx < n) ? counts[idx] : 0; }
  int tsum = v[0] + v[1] + v[2] + v[3];
  lds[t] = tsum;
  __syncthreads();
  for (int off = 1; off < 256; off <<= 1) {
    int x = (t >= off) ? lds[t - off] : 0;
    __syncthreads();
    lds[t] += x;
    __syncthreads();
  }
  int run = lds[t] - tsum;
  #pragma unroll
  for (int i = 0; i < 4; ++i) {
    int idx = base + i;
    if (idx < n) offs[idx] = run;
    run += v[i];
  }
  if (t == 255) bsum[b] = lds[255];
}

// Wave-parallel block-sum scan (nb <= 64 on this problem; serial fallback).
__global__ void k_scan2(int* __restrict__ bsum, int nb, int* __restrict__ offs, int n) {
  const int t = threadIdx.x;                  // 64 threads
  if (nb <= 64) {
    int v = (t < nb) ? bsum[t] : 0;
    int inc = v;
    #pragma unroll
    for (int off = 1; off < 64; off <<= 1) {
      int u = __shfl_up(inc, off);
      if (t >= off) inc += u;
    }
    if (t < nb) bsum[t] = inc - v;            // exclusive prefix
    int total = __shfl(inc, 63);
    if (t == 0) offs[n] = total;              // == E
  } else if (t == 0) {
    int run = 0;
    for (int b = 0; b < nb; ++b) { int x = bsum[b]; bsum[b] = run; run += x; }
    offs[n] = run;
  }
}

__global__ void k_scan3(int* __restrict__ offs, const int* __restrict__ bsum, int n) {
  int i = blockIdx.x * 256 + threadIdx.x;
  if (i < n) offs[i] += bsum[i >> 10];
}

__global__ void k_scatter(const int* __restrict__ src, const int* __restrict__ dst,
                          const int* __restrict__ offs, int* __restrict__ cursor,
                          int* __restrict__ csr_src, int E) {
  int i = blockIdx.x * 256 + threadIdx.x;
  if (i < E) {
    int d = dst[i];
    int pos = offs[d] + atomicAdd(&cursor[d], 1);
    csr_src[pos] = src[i];
  }
}

// ---------------------------------------------------------------------------
// GAT aggregation layer 1 — STANDALONE kernel (rule #19: the previous
// template<MEAN> co-compilation let the heavier MEAN=1 epilogue perturb
// BOTH instantiations' regalloc -> 8 B/thread spill = 100 MB scratch
// writes and +22 us. Separate kernels get independent codegen).
//   Pass 1 (h = t&3, j = t>>2 stride 64): w = exp(leaky(el+er)) -> sw4[j][h],
//     per-head denom partials -> sden[w][h]. No max-subtraction: scores are
//     O(+-3) for this model, exp is f32-safe, softmax ratio identical.
//   Pass 2: wave w walks edges j == w (mod 4); lane loads ushort4 (its 4
//     features of the 512 B row, head = lane>>4); weight = LDS broadcast.
//   Epilogue (wave 0): /denom, +res, +bias, ELU -> bf16 h1 row.
// ---------------------------------------------------------------------------
#define DCAP 128
__global__ __launch_bounds__(256) void agg_l1(
    const unsigned short* __restrict__ feat, const unsigned short* __restrict__ res,
    const float* __restrict__ el, const float* __restrict__ er,
    const float* __restrict__ bias, const int* __restrict__ csr_src,
    const int* __restrict__ offs, unsigned short* __restrict__ outbf)
{
  __shared__ int    ssrc[DCAP];
  __shared__ float  sw4[DCAP * 4];          // [j][h]
  __shared__ float  sden[4][4];             // [wave][h]
  __shared__ float4 sacc[4][64];            // [wave][lane]
  const int n = blockIdx.x;
  const int t = threadIdx.x;
  const int lane = t & 63, w = t >> 6;
  const int h = t & 3, j0 = t >> 2;
  const int hd = lane >> 4;
  const int s0  = offs[n];
  const int deg = offs[n + 1] - s0;         // >= 1 (self-loops)
  const bool cached = (deg <= DCAP);

  if (cached) {
    const float ernh = er[n * HEADS + h];
    float dp = 0.f;
    for (int j = j0; j < deg; j += 64) {
      int s = csr_src[s0 + j];
      float sc = el[s * HEADS + h] + ernh;
      sc = sc > 0.f ? sc : NEG_SLOPE * sc;  // leaky_relu
      float wv = __expf(sc);
      sw4[j * 4 + h] = wv;
      if (h == 0) ssrc[j] = s;
      dp += wv;
    }
    #pragma unroll
    for (int off = 4; off < 64; off <<= 1) dp += __shfl_xor(dp, off);
    if (lane < 4) sden[w][lane] = dp;
  }
  __syncthreads();

  float4 acc = make_float4(0.f, 0.f, 0.f, 0.f);
  if (cached) {
    int j = w;
    for (; j + 4 < deg; j += 8) {           // 2-way unroll
      int   sa = ssrc[j],         sb = ssrc[j + 4];
      float wa = sw4[j * 4 + hd], wb = sw4[(j + 4) * 4 + hd];
      ushort4 fa = *((const ushort4*)&feat[(size_t)sa * HF] + lane);
      ushort4 fb = *((const ushort4*)&feat[(size_t)sb * HF] + lane);
      acc.x = fmaf(wa, bf2f(fa.x), acc.x); acc.x = fmaf(wb, bf2f(fb.x), acc.x);
      acc.y = fmaf(wa, bf2f(fa.y), acc.y); acc.y = fmaf(wb, bf2f(fb.y), acc.y);
      acc.z = fmaf(wa, bf2f(fa.z), acc.z); acc.z = fmaf(wb, bf2f(fb.z), acc.z);
      acc.w = fmaf(wa, bf2f(fa.w), acc.w); acc.w = fmaf(wb, bf2f(fb.w), acc.w);
    }
    if (j < deg) {
      int   sa = ssrc[j];
      float wa = sw4[j * 4 + hd];
      ushort4 fa = *((const ushort4*)&feat[(size_t)sa * HF] + lane);
      acc.x = fmaf(wa, bf2f(fa.x), acc.x);
      acc.y = fmaf(wa, bf2f(fa.y), acc.y);
      acc.z = fmaf(wa, bf2f(fa.z), acc.z);
      acc.w = fmaf(wa, bf2f(fa.w), acc.w);
    }
  } else {                                  // rare deg>128 fallback
    const float ernd = er[n * HEADS + hd];
    float dpu = 0.f;
    for (int j = w; j < deg; j += 4) {
      int s = csr_src[s0 + j];
      float sc = el[s * HEADS + hd] + ernd;
      sc = sc > 0.f ? sc : NEG_SLOPE * sc;
      float wv = __expf(sc);
      dpu += wv;
      ushort4 fa = *((const ushort4*)&feat[(size_t)s * HF] + lane);
      acc.x = fmaf(wv, bf2f(fa.x), acc.x);
      acc.y = fmaf(wv, bf2f(fa.y), acc.y);
      acc.z = fmaf(wv, bf2f(fa.z), acc.z);
      acc.w = fmaf(wv, bf2f(fa.w), acc.w);
    }
    if ((lane & 15) == 0) sden[w][hd] = dpu;
  }
  sacc[w][lane] = acc;
  __syncthreads();

  if (w == 0) {
    float4 a0 = sacc[0][lane], a1 = sacc[1][lane],
           a2 = sacc[2][lane], a3 = sacc[3][lane];
    float denom = sden[0][hd] + sden[1][hd] + sden[2][hd] + sden[3][hd];
    float rden = 1.f / denom;
    ushort4 rv = *((const ushort4*)&res[(size_t)n * HF] + lane);
    float4  bv = *((const float4*)bias + lane);
    float v0 = (a0.x + a1.x + a2.x + a3.x) * rden + bf2f(rv.x) + bv.x;
    float v1 = (a0.y + a1.y + a2.y + a3.y) * rden + bf2f(rv.y) + bv.y;
    float v2 = (a0.z + a1.z + a2.z + a3.z) * rden + bf2f(rv.z) + bv.z;
    float v3 = (a0.w + a1.w + a2.w + a3.w) * rden + bf2f(rv.w) + bv.w;
    v0 = v0 > 0.f ? v0 : expm1f(v0);        // ELU(alpha=1)
    v1 = v1 > 0.f ? v1 : expm1f(v1);
    v2 = v2 > 0.f ? v2 : expm1f(v2);
    v3 = v3 > 0.f ? v3 : expm1f(v3);
    ushort4 o;
    o.x = f2bf(v0); o.y = f2bf(v1); o.z = f2bf(v2); o.w = f2bf(v3);
    *((ushort4*)&outbf[(size_t)n * HF] + lane) = o;
  }
}

// ---------------------------------------------------------------------------
// GAT aggregation layer 2 — STANDALONE kernel: same core, head-mean epilogue
// + FUSED WeightedSumAndMax readout (atomicAdd wsum, encoded atomicMax hmax).
// ---------------------------------------------------------------------------
__global__ __launch_bounds__(256) void agg_l2(
    const unsigned short* __restrict__ feat, const unsigned short* __restrict__ res,
    const float* __restrict__ el, const float* __restrict__ er,
    const float* __restrict__ bias, const int* __restrict__ csr_src,
    const int* __restrict__ offs, const int* __restrict__ gid,
    const float* __restrict__ Ww, const float* __restrict__ bw,
    float* __restrict__ wsum, unsigned* __restrict__ hmax)
{
  __shared__ int    ssrc[DCAP];
  __shared__ float  sw4[DCAP * 4];
  __shared__ float  sden[4][4];
  __shared__ float4 sacc[4][64];
  const int n = blockIdx.x;
  const int t = threadIdx.x;
  const int lane = t & 63, w = t >> 6;
  const int h = t & 3, j0 = t >> 2;
  const int hd = lane >> 4;
  const int s0  = offs[n];
  const int deg = offs[n + 1] - s0;
  const bool cached = (deg <= DCAP);

  if (cached) {
    const float ernh = er[n * HEADS + h];
    float dp = 0.f;
    for (int j = j0; j < deg; j += 64) {
      int s = csr_src[s0 + j];
      float sc = el[s * HEADS + h] + ernh;
      sc = sc > 0.f ? sc : NEG_SLOPE * sc;
      float wv = __expf(sc);
      sw4[j * 4 + h] = wv;
      if (h == 0) ssrc[j] = s;
      dp += wv;
    }
    #pragma unroll
    for (int off = 4; off < 64; off <<= 1) dp += __shfl_xor(dp, off);
    if (lane < 4) sden[w][lane] = dp;
  }
  __syncthreads();

  float4 acc = make_float4(0.f, 0.f, 0.f, 0.f);
  if (cached) {
    int j = w;
    for (; j + 4 < deg; j += 8) {
      int   sa = ssrc[j],         sb = ssrc[j + 4];
      float wa = sw4[j * 4 + hd], wb = sw4[(j + 4) * 4 + hd];
      ushort4 fa = *((const ushort4*)&feat[(size_t)sa * HF] + lane);
      ushort4 fb = *((const ushort4*)&feat[(size_t)sb * HF] + lane);
      acc.x = fmaf(wa, bf2f(fa.x), acc.x); acc.x = fmaf(wb, bf2f(fb.x), acc.x);
      acc.y = fmaf(wa, bf2f(fa.y), acc.y); acc.y = fmaf(wb, bf2f(fb.y), acc.y);
      acc.z = fmaf(wa, bf2f(fa.z), acc.z); acc.z = fmaf(wb, bf2f(fb.z), acc.z);
      acc.w = fmaf(wa, bf2f(fa.w), acc.w); acc.w = fmaf(wb, bf2f(fb.w), acc.w);
    }
    if (j < deg) {
      int   sa = ssrc[j];
      float wa = sw4[j * 4 + hd];
      ushort4 fa = *((const ushort4*)&feat[(size_t)sa * HF] + lane);
      acc.x = fmaf(wa, bf2f(fa.x), acc.x);
      acc.y = fmaf(wa, bf2f(fa.y), acc.y);
      acc.z = fmaf(wa, bf2f(fa.z), acc.z);
      acc.w = fmaf(wa, bf2f(fa.w), acc.w);
    }
  } else {
    const float ernd = er[n * HEADS + hd];
    float dpu = 0.f;
    for (int j = w; j < deg; j += 4) {
      int s = csr_src[s0 + j];
      float sc = el[s * HEADS + hd] + ernd;
      sc = sc > 0.f ? sc : NEG_SLOPE * sc;
      float wv = __expf(sc);
      dpu += wv;
      ushort4 fa = *((const ushort4*)&feat[(size_t)s * HF] + lane);
      acc.x = fmaf(wv, bf2f(fa.x), acc.x);
      acc.y = fmaf(wv, bf2f(fa.y), acc.y);
      acc.z = fmaf(wv, bf2f(fa.z), acc.z);
      acc.w = fmaf(wv, bf2f(fa.w), acc.w);
    }
    if ((lane & 15) == 0) sden[w][hd] = dpu;
  }
  sacc[w][lane] = acc;
  __syncthreads();

  if (w == 0) {
    float4 a0 = sacc[0][lane], a1 = sacc[1][lane],
           a2 = sacc[2][lane], a3 = sacc[3][lane];
    float denom = sden[0][hd] + sden[1][hd] + sden[2][hd] + sden[3][hd];
    float rden = 1.f / denom;
    ushort4 rv = *((const ushort4*)&res[(size_t)n * HF] + lane);
    float4  bv = *((const float4*)bias + lane);
    float v0 = (a0.x + a1.x + a2.x + a3.x) * rden + bf2f(rv.x) + bv.x;
    float v1 = (a0.y + a1.y + a2.y + a3.y) * rden + bf2f(rv.y) + bv.y;
    float v2 = (a0.z + a1.z + a2.z + a3.z) * rden + bf2f(rv.z) + bv.z;
    float v3 = (a0.w + a1.w + a2.w + a3.w) * rden + bf2f(rv.w) + bv.w;
    v0 = v0 > 0.f ? v0 : expm1f(v0);        // ELU(alpha=1)
    v1 = v1 > 0.f ? v1 : expm1f(v1);
    v2 = v2 > 0.f ? v2 : expm1f(v2);
    v3 = v3 > 0.f ? v3 : expm1f(v3);
    #pragma unroll
    for (int off = 16; off < 64; off <<= 1) {     // sum across the 4 heads
      v0 += __shfl_xor(v0, off);
      v1 += __shfl_xor(v1, off);
      v2 += __shfl_xor(v2, off);
      v3 += __shfl_xor(v3, off);
    }
    if (lane < 16) {                        // h2 row lives in lanes 0-15
      const float h0 = 0.25f * v0, h1 = 0.25f * v1,
                  h2 = 0.25f * v2, h3 = 0.25f * v3;
      const float4 wwv = ((const float4*)Ww)[lane];
      float part = h0 * wwv.x + h1 * wwv.y + h2 * wwv.z + h3 * wwv.w;
      #pragma unroll
      for (int off = 1; off < 16; off <<= 1)
        part += __shfl_xor(part, off);
      const float wgt = 1.f / (1.f + __expf(-(part + bw[0])));
      const int g = gid[n];
      float* wp = &wsum[g * FD + lane * 4];
      atomicAdd(wp + 0, h0 * wgt);
      atomicAdd(wp + 1, h1 * wgt);
      atomicAdd(wp + 2, h2 * wgt);
      atomicAdd(wp + 3, h3 * wgt);
      unsigned* hp = &hmax[g * FD + lane * 4];
      unsigned u0 = __float_as_uint(h0), u1 = __float_as_uint(h1),
               u2 = __float_as_uint(h2), u3 = __float_as_uint(h3);
      atomicMax(hp + 0, (u0 & 0x80000000u) ? ~u0 : (u0 | 0x80000000u));
      atomicMax(hp + 1, (u1 & 0x80000000u) ? ~u1 : (u1 | 0x80000000u));
      atomicMax(hp + 2, (u2 & 0x80000000u) ? ~u2 : (u2 | 0x80000000u));
      atomicMax(hp + 3, (u3 & 0x80000000u) ? ~u3 : (u3 | 0x80000000u));
    }
  }
}

// ---------------------------------------------------------------------------
// Predictor.
// ---------------------------------------------------------------------------
__global__ __launch_bounds__(64) void k_predict(
    const float* __restrict__ wsum, const unsigned* __restrict__ hmax,
    const float* __restrict__ Wp1, const float* __restrict__ bp1,
    const float* __restrict__ Wp2, const float* __restrict__ bp2,
    float* __restrict__ out)
{
  const int g = blockIdx.x, t = threadIdx.x;
  float acc = 0.f;
  if (t < 32) {
    acc = bp1[t];
    #pragma unroll 4
    for (int k = 0; k < FD; ++k)
      acc = fmaf(wsum[g * FD + k], Wp1[k * 32 + t], acc);
    #pragma unroll 4
    for (int k = 0; k < FD; ++k) {
      unsigned e = hmax[g * FD + k];
      float hv = (e & 0x80000000u) ? __uint_as_float(e & 0x7FFFFFFFu)
                                   : __uint_as_float(~e);
      acc = fmaf(hv, Wp1[(FD + k) * 32 + t], acc);
    }
    acc = fmaxf(acc, 0.f) * Wp2[t];
  }
  acc = wave_sum(acc);
  if (t == 0) out[g] = acc + bp2[0];
}

// ---------------------------------------------------------------------------
extern "C" void kernel_launch(void* const* d_in, const int* in_sizes, int n_in,
                              void* d_out, int out_size, void* d_ws, size_t ws_size,
                              hipStream_t stream) {
  const float* x     = (const float*)d_in[0];
  const int*   src   = (const int*)  d_in[1];
  const int*   dst   = (const int*)  d_in[2];
  const int*   gid   = (const int*)  d_in[3];
  const float* W1    = (const float*)d_in[4];
  const float* al1   = (const float*)d_in[5];
  const float* ar1   = (const float*)d_in[6];
  const float* b1    = (const float*)d_in[7];
  const float* Wres1 = (const float*)d_in[8];
  const float* W2    = (const float*)d_in[9];
  const float* al2   = (const float*)d_in[10];
  const float* ar2   = (const float*)d_in[11];
  const float* b2    = (const float*)d_in[12];
  const float* Wres2 = (const float*)d_in[13];
  const float* Ww    = (const float*)d_in[14];
  const float* bw    = (const float*)d_in[15];
  const float* Wp1   = (const float*)d_in[16];
  const float* bp1   = (const float*)d_in[17];
  const float* Wp2   = (const float*)d_in[18];
  const float* bp2   = (const float*)d_in[19];
  float* out = (float*)d_out;

  const int N = in_sizes[3];        // gid has N elements
  const int E = in_sizes[1];        // src has E elements
  const int G = out_size;           // output is [G,1]
  const int Mpad = (N + 127) & ~127;
  const int GFD  = G * FD;

  // ---- workspace carve (256B-aligned) ----
  char* p = (char*)d_ws;
  auto alloc = [&](size_t bytes) {
    char* r = p;
    p += (bytes + 255) & ~(size_t)255;
    return r;
  };
  unsigned short* featbf  = (unsigned short*)alloc((size_t)Mpad * HF * 2);
  unsigned short* resbf   = (unsigned short*)alloc((size_t)Mpad * HF * 2);
  float*          el      = (float*)         alloc((size_t)N * HEADS * 4);
  float*          er      = (float*)         alloc((size_t)N * HEADS * 4);
  int*            counts  = (int*)           alloc((size_t)N * 4);
  int*            cursor  = (int*)           alloc((size_t)N * 4);
  int*            offs    = (int*)           alloc((size_t)(N + 1) * 4);
  const int nb            = (N + 1023) / 1024;
  int*            bsum    = (int*)           alloc((size_t)nb * 4);
  int*            csr_src = (int*)           alloc((size_t)E * 4);
  float*          wsum    = (float*)         alloc((size_t)GFD * 4);
  unsigned*       hmax    = (unsigned*)      alloc((size_t)GFD * 4);
  unsigned short* xbf     = (unsigned short*)alloc((size_t)Mpad * 64 * 2);
  unsigned short* h1bf    = (unsigned short*)alloc((size_t)Mpad * HF * 2);
  unsigned short* BT1     = (unsigned short*)alloc((size_t)512 * 64 * 2);
  unsigned short* BT2     = (unsigned short*)alloc((size_t)512 * 256 * 2);
  (void)ws_size; (void)n_in;

  // ---- conversions + all scratch init (one kernel) ----
  const int n4 = N * 64 / 4;
  const int init_total = n4 + 512 * 64 + 512 * 256 + N + N + GFD + GFD;
  k_cvt_init<<<(init_total + 255) / 256, 256, 0, stream>>>(
      x, W1, Wres1, W2, Wres2, xbf, BT1, BT2,
      counts, cursor, wsum, hmax, n4, N, GFD);

  // ---- CSR by destination (shared by both layers) ----
  k_hist   <<<(E + 255) / 256, 256, 0, stream>>>(dst, counts, E);
  k_scan1  <<<nb, 256, 0, stream>>>(counts, offs, bsum, N);
  k_scan2  <<<1, 64, 0, stream>>>(bsum, nb, offs, N);
  k_scan3  <<<(N + 255) / 256, 256, 0, stream>>>(offs, bsum, N);
  k_scatter<<<(E + 255) / 256, 256, 0, stream>>>(src, dst, offs, cursor, csr_src, E);

  dim3 gg(Mpad / 128, 4);

  // ---- layer 1 (flatten) ----
  gemm_mfma<64> <<<gg, 256, 0, stream>>>(xbf, BT1, al1, ar1,
                                         featbf, resbf, el, er, N);
  agg_l1        <<<N, 256, 0, stream>>>(featbf, resbf, el, er, b1, csr_src,
                                        offs, h1bf);

  // ---- layer 2 (mean) + fused readout ----
  gemm_mfma<256><<<gg, 256, 0, stream>>>(h1bf, BT2, al2, ar2,
                                         featbf, resbf, el, er, N);
  agg_l2        <<<N, 256, 0, stream>>>(featbf, resbf, el, er, b2, csr_src,
                                        offs, gid, Ww, bw, wsum, hmax);

  // ---- predictor ----
  k_predict<<<G, 64, 0, stream>>>(wsum, hmax, Wp1, bp1, Wp2, bp2, out);
}

// Round 13
// 336.530 us; speedup vs baseline: 1.0812x; 1.0812x over previous
//
#include <hip/hip_runtime.h>
#include <hip/hip_bf16.h>
#include <math.h>

// Problem constants (from reference): H=4 heads, F=64 per-head, H*F=256.
#define HF    256
#define HEADS 4
#define FD    64
#define NEG_SLOPE 0.2f

typedef __attribute__((ext_vector_type(8))) short short8;
typedef __attribute__((ext_vector_type(4))) float f32x4;

__device__ __forceinline__ float wave_sum(float v) {
  #pragma unroll
  for (int off = 32; off; off >>= 1) v += __shfl_xor(v, off);
  return v;
}

// f32 -> bf16 round-to-nearest-even (raw bits).
__device__ __forceinline__ unsigned short f2bf(float f) {
  unsigned u = __float_as_uint(f);
  u += 0x7FFFu + ((u >> 16) & 1u);
  return (unsigned short)(u >> 16);
}
__device__ __forceinline__ float bf2f(unsigned short u) {
  return __uint_as_float((unsigned)u << 16);
}

// async global->LDS, 16 B per lane (wave-uniform LDS base + lane*16).
__device__ __forceinline__ void gload_lds16(const void* g, void* l) {
  __builtin_amdgcn_global_load_lds((const unsigned int*)g, (unsigned int*)l,
                                   16, 0, 0);
}

// ---------------------------------------------------------------------------
// bf16 MFMA GEMM: C[Mpad x 512] = A[Mpad x K] @ B[K x 512], B given
// pre-transposed as BT[512 x K]. Output cols 0..255 -> featbf, 256..511 ->
// resbf (both bf16). For the feat half, each wave owns exactly one head's 64
// columns -> el/er computed in-register (16-lane shfl reduce over f32 acc).
// 128x128 tile, 4 waves (2x2), 4x4 fragments of 16x16x32, BK=32 (m97-lite).
// ---------------------------------------------------------------------------
template<int K>
__global__ __launch_bounds__(256) void gemm_mfma(
    const unsigned short* __restrict__ A,   // [Mpad][K] bf16 bits
    const unsigned short* __restrict__ BT,  // [512][K]  bf16 bits
    const float* __restrict__ al, const float* __restrict__ ar,
    unsigned short* __restrict__ featbf, unsigned short* __restrict__ resbf,
    float* __restrict__ el, float* __restrict__ er, int M)
{
  __shared__ __align__(16) unsigned short As[128 * 32];
  __shared__ __align__(16) unsigned short Bs[128 * 32];
  const int t    = threadIdx.x;
  const int lane = t & 63, w = t >> 6;
  const int wr = w >> 1, wc = w & 1;
  const int l15 = lane & 15, lhi = lane >> 4;
  const int row0 = blockIdx.x * 128;
  const int n0b  = blockIdx.y;             // 0,1 -> feat; 2,3 -> res

  // staging chunks: 512 chunks of 16B per tile; chunk c: row=c>>2, col8=(c&3)*8
  const int c0 = w * 128 + lane;
  const int c1 = c0 + 64;
  const unsigned short* gA0 = A  + (size_t)(row0 + (c0 >> 2)) * K + (c0 & 3) * 8;
  const unsigned short* gA1 = A  + (size_t)(row0 + (c1 >> 2)) * K + (c1 & 3) * 8;
  const unsigned short* gB0 = BT + (size_t)(n0b * 128 + (c0 >> 2)) * K + (c0 & 3) * 8;
  const unsigned short* gB1 = BT + (size_t)(n0b * 128 + (c1 >> 2)) * K + (c1 & 3) * 8;
  unsigned short* lA0 = &As[w * 1024];
  unsigned short* lA1 = &As[w * 1024 + 512];
  unsigned short* lB0 = &Bs[w * 1024];
  unsigned short* lB1 = &Bs[w * 1024 + 512];

  f32x4 acc[4][4];
  #pragma unroll
  for (int i = 0; i < 4; ++i)
    #pragma unroll
    for (int j = 0; j < 4; ++j)
      acc[i][j] = (f32x4){0.f, 0.f, 0.f, 0.f};

  for (int k0 = 0; k0 < K; k0 += 32) {
    __syncthreads();                       // prev iter's ds_reads done
    gload_lds16(gA0 + k0, lA0);
    gload_lds16(gA1 + k0, lA1);
    gload_lds16(gB0 + k0, lB0);
    gload_lds16(gB1 + k0, lB1);
    __syncthreads();                       // drains vmcnt -> LDS tiles ready

    short8 a[4], b[4];
    #pragma unroll
    for (int im = 0; im < 4; ++im)
      a[im] = *(const short8*)&As[(wr * 64 + im * 16 + l15) * 32 + lhi * 8];
    #pragma unroll
    for (int jn = 0; jn < 4; ++jn)
      b[jn] = *(const short8*)&Bs[(wc * 64 + jn * 16 + l15) * 32 + lhi * 8];
    #pragma unroll
    for (int im = 0; im < 4; ++im)
      #pragma unroll
      for (int jn = 0; jn < 4; ++jn)
        acc[im][jn] = __builtin_amdgcn_mfma_f32_16x16x32_bf16(
            a[im], b[jn], acc[im][jn], 0, 0, 0);
  }

  // C/D layout: col = lane&15, row = (lane>>4)*4 + q   [m89/m91 verified]
  unsigned short* outp = (n0b < 2) ? featbf : resbf;
  const int colbase = (n0b & 1) * 128 + wc * 64;
  #pragma unroll
  for (int im = 0; im < 4; ++im) {
    const int rowb = row0 + wr * 64 + im * 16 + lhi * 4;
    #pragma unroll
    for (int q = 0; q < 4; ++q) {
      if (rowb + q < M) {
        unsigned short* rp = outp + (size_t)(rowb + q) * HF + colbase;
        #pragma unroll
        for (int jn = 0; jn < 4; ++jn)
          rp[jn * 16 + l15] = f2bf(acc[im][jn][q]);
      }
    }
  }

  // el/er for the feat half: wave (n0b,wc) owns head hd's full 64 columns.
  if (n0b < 2) {
    const int hd = n0b * 2 + wc;
    float alv[4], arv[4];
    #pragma unroll
    for (int jn = 0; jn < 4; ++jn) {
      alv[jn] = al[hd * FD + jn * 16 + l15];
      arv[jn] = ar[hd * FD + jn * 16 + l15];
    }
    #pragma unroll
    for (int im = 0; im < 4; ++im) {
      #pragma unroll
      for (int q = 0; q < 4; ++q) {
        float es = 0.f, rs = 0.f;
        #pragma unroll
        for (int jn = 0; jn < 4; ++jn) {
          es = fmaf(acc[im][jn][q], alv[jn], es);
          rs = fmaf(acc[im][jn][q], arv[jn], rs);
        }
        #pragma unroll
        for (int off = 1; off < 16; off <<= 1) {   // reduce across l15 group
          es += __shfl_xor(es, off);
          rs += __shfl_xor(rs, off);
        }
        const int row = row0 + wr * 64 + im * 16 + lhi * 4 + q;
        if (l15 == 0 && row < M) {
          el[row * HEADS + hd] = es;
          er[row * HEADS + hd] = rs;
        }
      }
    }
  }
}

// ---------------------------------------------------------------------------
// Fused conversions + scratch init + graph-offset build (gid is SORTED):
// x->bf16 | BT1 | BT2 | counts=0 | cursor=0 | goffs boundary-fill.
// goffs[g] = first node index with gid >= g; graph g = [goffs[g], goffs[g+1]).
// ---------------------------------------------------------------------------
__global__ void k_cvt_init(
    const float* __restrict__ x,
    const float* __restrict__ W1, const float* __restrict__ Wres1,
    const float* __restrict__ W2, const float* __restrict__ Wres2,
    unsigned short* __restrict__ xbf, unsigned short* __restrict__ BT1,
    unsigned short* __restrict__ BT2, int* __restrict__ counts,
    int* __restrict__ cursor, const int* __restrict__ gid,
    int* __restrict__ goffs, int n4, int N, int G)
{
  int i = blockIdx.x * 256 + threadIdx.x;
  if (i < n4) {
    float4 v = ((const float4*)x)[i];
    ushort4 o;
    o.x = f2bf(v.x); o.y = f2bf(v.y); o.z = f2bf(v.z); o.w = f2bf(v.w);
    ((ushort4*)xbf)[i] = o;
    return;
  }
  i -= n4;
  if (i < 512 * 64) {
    int j = i >> 6, k = i & 63;
    float v = (j < HF) ? W1[k * HF + j] : Wres1[k * HF + (j - HF)];
    BT1[i] = f2bf(v);
    return;
  }
  i -= 512 * 64;
  if (i < 512 * 256) {
    int j = i >> 8, k = i & 255;
    float v = (j < HF) ? W2[k * HF + j] : Wres2[k * HF + (j - HF)];
    BT2[i] = f2bf(v);
    return;
  }
  i -= 512 * 256;
  if (i < N) { counts[i] = 0; return; }
  i -= N;
  if (i < N) { cursor[i] = 0; return; }
  i -= N;
  if (i < N) {
    const int g1 = gid[i];
    if (i == 0) {
      for (int g = 0; g <= g1; ++g) goffs[g] = 0;
    } else {
      const int g0 = gid[i - 1];
      for (int g = g0 + 1; g <= g1; ++g) goffs[g] = i;
    }
    if (i == N - 1) {
      for (int g = g1 + 1; g <= G; ++g) goffs[g] = N;
    }
  }
}

// ---------------------------------------------------------------------------
// CSR build: histogram -> 2-level exclusive scan -> scatter.
// ---------------------------------------------------------------------------
__global__ void k_hist(const int* __restrict__ dst, int* __restrict__ counts, int E) {
  int i = blockIdx.x * 256 + threadIdx.x;
  if (i < E) atomicAdd(&counts[dst[i]], 1);
}

__global__ __launch_bounds__(256) void k_scan1(
    const int* __restrict__ counts, int* __restrict__ offs,
    int* __restrict__ bsum, int n)
{
  __shared__ int lds[256];
  const int b = blockIdx.x, t = threadIdx.x;
  const int base = b * 1024 + t * 4;
  int v[4];
  #pragma unroll
  for (int i = 0; i < 4; ++i) { int idx = base + i; v[i] = (idx < n) ? counts[idx] : 0; }
  int tsum = v[0] + v[1] + v[2] + v[3];
  lds[t] = tsum;
  __syncthreads();
  for (int off = 1; off < 256; off <<= 1) {
    int x = (t >= off) ? lds[t - off] : 0;
    __syncthreads();
    lds[t] += x;
    __syncthreads();
  }
  int run = lds[t] - tsum;
  #pragma unroll
  for (int i = 0; i < 4; ++i) {
    int idx = base + i;
    if (idx < n) offs[idx] = run;
    run += v[i];
  }
  if (t == 255) bsum[b] = lds[255];
}

// Wave-parallel block-sum scan (nb <= 64 on this problem; serial fallback).
__global__ void k_scan2(int* __restrict__ bsum, int nb, int* __restrict__ offs, int n) {
  const int t = threadIdx.x;                  // 64 threads
  if (nb <= 64) {
    int v = (t < nb) ? bsum[t] : 0;
    int inc = v;
    #pragma unroll
    for (int off = 1; off < 64; off <<= 1) {
      int u = __shfl_up(inc, off);
      if (t >= off) inc += u;
    }
    if (t < nb) bsum[t] = inc - v;            // exclusive prefix
    int total = __shfl(inc, 63);
    if (t == 0) offs[n] = total;              // == E
  } else if (t == 0) {
    int run = 0;
    for (int b = 0; b < nb; ++b) { int x = bsum[b]; bsum[b] = run; run += x; }
    offs[n] = run;
  }
}

__global__ void k_scan3(int* __restrict__ offs, const int* __restrict__ bsum, int n) {
  int i = blockIdx.x * 256 + threadIdx.x;
  if (i < n) offs[i] += bsum[i >> 10];
}

__global__ void k_scatter(const int* __restrict__ src, const int* __restrict__ dst,
                          const int* __restrict__ offs, int* __restrict__ cursor,
                          int* __restrict__ csr_src, int E) {
  int i = blockIdx.x * 256 + threadIdx.x;
  if (i < E) {
    int d = dst[i];
    int pos = offs[d] + atomicAdd(&cursor[d], 1);
    csr_src[pos] = src[i];
  }
}

// ---------------------------------------------------------------------------
// GAT aggregation layer 1 — standalone (rule #19: independent codegen).
//   Pass 1 (h = t&3, j = t>>2 stride 64): w = exp(leaky(el+er)) -> sw4[j][h],
//     per-head denom partials -> sden[w][h]. No max-subtraction: scores are
//     O(+-3) for this model, exp is f32-safe, softmax ratio identical.
//   Pass 2: wave w walks edges j == w (mod 4); lane loads ushort4 (its 4
//     features of the 512 B row, head = lane>>4); weight = LDS broadcast.
//   Epilogue (wave 0): /denom, +res, +bias, ELU -> bf16 h1 row.
// ---------------------------------------------------------------------------
#define DCAP 128
__global__ __launch_bounds__(256) void agg_l1(
    const unsigned short* __restrict__ feat, const unsigned short* __restrict__ res,
    const float* __restrict__ el, const float* __restrict__ er,
    const float* __restrict__ bias, const int* __restrict__ csr_src,
    const int* __restrict__ offs, unsigned short* __restrict__ outbf)
{
  __shared__ int    ssrc[DCAP];
  __shared__ float  sw4[DCAP * 4];          // [j][h]
  __shared__ float  sden[4][4];             // [wave][h]
  __shared__ float4 sacc[4][64];            // [wave][lane]
  const int n = blockIdx.x;
  const int t = threadIdx.x;
  const int lane = t & 63, w = t >> 6;
  const int h = t & 3, j0 = t >> 2;
  const int hd = lane >> 4;
  const int s0  = offs[n];
  const int deg = offs[n + 1] - s0;         // >= 1 (self-loops)
  const bool cached = (deg <= DCAP);

  if (cached) {
    const float ernh = er[n * HEADS + h];
    float dp = 0.f;
    for (int j = j0; j < deg; j += 64) {
      int s = csr_src[s0 + j];
      float sc = el[s * HEADS + h] + ernh;
      sc = sc > 0.f ? sc : NEG_SLOPE * sc;  // leaky_relu
      float wv = __expf(sc);
      sw4[j * 4 + h] = wv;
      if (h == 0) ssrc[j] = s;
      dp += wv;
    }
    #pragma unroll
    for (int off = 4; off < 64; off <<= 1) dp += __shfl_xor(dp, off);
    if (lane < 4) sden[w][lane] = dp;
  }
  __syncthreads();

  float4 acc = make_float4(0.f, 0.f, 0.f, 0.f);
  if (cached) {
    int j = w;
    for (; j + 4 < deg; j += 8) {           // 2-way unroll
      int   sa = ssrc[j],         sb = ssrc[j + 4];
      float wa = sw4[j * 4 + hd], wb = sw4[(j + 4) * 4 + hd];
      ushort4 fa = *((const ushort4*)&feat[(size_t)sa * HF] + lane);
      ushort4 fb = *((const ushort4*)&feat[(size_t)sb * HF] + lane);
      acc.x = fmaf(wa, bf2f(fa.x), acc.x); acc.x = fmaf(wb, bf2f(fb.x), acc.x);
      acc.y = fmaf(wa, bf2f(fa.y), acc.y); acc.y = fmaf(wb, bf2f(fb.y), acc.y);
      acc.z = fmaf(wa, bf2f(fa.z), acc.z); acc.z = fmaf(wb, bf2f(fb.z), acc.z);
      acc.w = fmaf(wa, bf2f(fa.w), acc.w); acc.w = fmaf(wb, bf2f(fb.w), acc.w);
    }
    if (j < deg) {
      int   sa = ssrc[j];
      float wa = sw4[j * 4 + hd];
      ushort4 fa = *((const ushort4*)&feat[(size_t)sa * HF] + lane);
      acc.x = fmaf(wa, bf2f(fa.x), acc.x);
      acc.y = fmaf(wa, bf2f(fa.y), acc.y);
      acc.z = fmaf(wa, bf2f(fa.z), acc.z);
      acc.w = fmaf(wa, bf2f(fa.w), acc.w);
    }
  } else {                                  // rare deg>128 fallback
    const float ernd = er[n * HEADS + hd];
    float dpu = 0.f;
    for (int j = w; j < deg; j += 4) {
      int s = csr_src[s0 + j];
      float sc = el[s * HEADS + hd] + ernd;
      sc = sc > 0.f ? sc : NEG_SLOPE * sc;
      float wv = __expf(sc);
      dpu += wv;
      ushort4 fa = *((const ushort4*)&feat[(size_t)s * HF] + lane);
      acc.x = fmaf(wv, bf2f(fa.x), acc.x);
      acc.y = fmaf(wv, bf2f(fa.y), acc.y);
      acc.z = fmaf(wv, bf2f(fa.z), acc.z);
      acc.w = fmaf(wv, bf2f(fa.w), acc.w);
    }
    if ((lane & 15) == 0) sden[w][hd] = dpu;
  }
  sacc[w][lane] = acc;
  __syncthreads();

  if (w == 0) {
    float4 a0 = sacc[0][lane], a1 = sacc[1][lane],
           a2 = sacc[2][lane], a3 = sacc[3][lane];
    float denom = sden[0][hd] + sden[1][hd] + sden[2][hd] + sden[3][hd];
    float rden = 1.f / denom;
    ushort4 rv = *((const ushort4*)&res[(size_t)n * HF] + lane);
    float4  bv = *((const float4*)bias + lane);
    float v0 = (a0.x + a1.x + a2.x + a3.x) * rden + bf2f(rv.x) + bv.x;
    float v1 = (a0.y + a1.y + a2.y + a3.y) * rden + bf2f(rv.y) + bv.y;
    float v2 = (a0.z + a1.z + a2.z + a3.z) * rden + bf2f(rv.z) + bv.z;
    float v3 = (a0.w + a1.w + a2.w + a3.w) * rden + bf2f(rv.w) + bv.w;
    v0 = v0 > 0.f ? v0 : expm1f(v0);        // ELU(alpha=1)
    v1 = v1 > 0.f ? v1 : expm1f(v1);
    v2 = v2 > 0.f ? v2 : expm1f(v2);
    v3 = v3 > 0.f ? v3 : expm1f(v3);
    ushort4 o;
    o.x = f2bf(v0); o.y = f2bf(v1); o.z = f2bf(v2); o.w = f2bf(v3);
    *((ushort4*)&outbf[(size_t)n * HF] + lane) = o;
  }
}

// ---------------------------------------------------------------------------
// GAT aggregation layer 2 — same core; epilogue writes the f32 h2 row plus
// node_w[n] = sigmoid(dot(h2row, Ww)+bw). NO ATOMICS (the previous fused
// atomic readout's 6.4M device-scope atomics = the 100000 KB WRITE_SIZE
// signature and +25 us vs agg_l1; gid is sorted so segment reduction moves
// to a per-graph wave kernel instead).
// ---------------------------------------------------------------------------
__global__ __launch_bounds__(256) void agg_l2(
    const unsigned short* __restrict__ feat, const unsigned short* __restrict__ res,
    const float* __restrict__ el, const float* __restrict__ er,
    const float* __restrict__ bias, const int* __restrict__ csr_src,
    const int* __restrict__ offs, const float* __restrict__ Ww,
    const float* __restrict__ bw, float* __restrict__ h2out,
    float* __restrict__ node_w)
{
  __shared__ int    ssrc[DCAP];
  __shared__ float  sw4[DCAP * 4];
  __shared__ float  sden[4][4];
  __shared__ float4 sacc[4][64];
  const int n = blockIdx.x;
  const int t = threadIdx.x;
  const int lane = t & 63, w = t >> 6;
  const int h = t & 3, j0 = t >> 2;
  const int hd = lane >> 4;
  const int s0  = offs[n];
  const int deg = offs[n + 1] - s0;
  const bool cached = (deg <= DCAP);

  if (cached) {
    const float ernh = er[n * HEADS + h];
    float dp = 0.f;
    for (int j = j0; j < deg; j += 64) {
      int s = csr_src[s0 + j];
      float sc = el[s * HEADS + h] + ernh;
      sc = sc > 0.f ? sc : NEG_SLOPE * sc;
      float wv = __expf(sc);
      sw4[j * 4 + h] = wv;
      if (h == 0) ssrc[j] = s;
      dp += wv;
    }
    #pragma unroll
    for (int off = 4; off < 64; off <<= 1) dp += __shfl_xor(dp, off);
    if (lane < 4) sden[w][lane] = dp;
  }
  __syncthreads();

  float4 acc = make_float4(0.f, 0.f, 0.f, 0.f);
  if (cached) {
    int j = w;
    for (; j + 4 < deg; j += 8) {
      int   sa = ssrc[j],         sb = ssrc[j + 4];
      float wa = sw4[j * 4 + hd], wb = sw4[(j + 4) * 4 + hd];
      ushort4 fa = *((const ushort4*)&feat[(size_t)sa * HF] + lane);
      ushort4 fb = *((const ushort4*)&feat[(size_t)sb * HF] + lane);
      acc.x = fmaf(wa, bf2f(fa.x), acc.x); acc.x = fmaf(wb, bf2f(fb.x), acc.x);
      acc.y = fmaf(wa, bf2f(fa.y), acc.y); acc.y = fmaf(wb, bf2f(fb.y), acc.y);
      acc.z = fmaf(wa, bf2f(fa.z), acc.z); acc.z = fmaf(wb, bf2f(fb.z), acc.z);
      acc.w = fmaf(wa, bf2f(fa.w), acc.w); acc.w = fmaf(wb, bf2f(fb.w), acc.w);
    }
    if (j < deg) {
      int   sa = ssrc[j];
      float wa = sw4[j * 4 + hd];
      ushort4 fa = *((const ushort4*)&feat[(size_t)sa * HF] + lane);
      acc.x = fmaf(wa, bf2f(fa.x), acc.x);
      acc.y = fmaf(wa, bf2f(fa.y), acc.y);
      acc.z = fmaf(wa, bf2f(fa.z), acc.z);
      acc.w = fmaf(wa, bf2f(fa.w), acc.w);
    }
  } else {
    const float ernd = er[n * HEADS + hd];
    float dpu = 0.f;
    for (int j = w; j < deg; j += 4) {
      int s = csr_src[s0 + j];
      float sc = el[s * HEADS + hd] + ernd;
      sc = sc > 0.f ? sc : NEG_SLOPE * sc;
      float wv = __expf(sc);
      dpu += wv;
      ushort4 fa = *((const ushort4*)&feat[(size_t)s * HF] + lane);
      acc.x = fmaf(wv, bf2f(fa.x), acc.x);
      acc.y = fmaf(wv, bf2f(fa.y), acc.y);
      acc.z = fmaf(wv, bf2f(fa.z), acc.z);
      acc.w = fmaf(wv, bf2f(fa.w), acc.w);
    }
    if ((lane & 15) == 0) sden[w][hd] = dpu;
  }
  sacc[w][lane] = acc;
  __syncthreads();

  if (w == 0) {
    float4 a0 = sacc[0][lane], a1 = sacc[1][lane],
           a2 = sacc[2][lane], a3 = sacc[3][lane];
    float denom = sden[0][hd] + sden[1][hd] + sden[2][hd] + sden[3][hd];
    float rden = 1.f / denom;
    ushort4 rv = *((const ushort4*)&res[(size_t)n * HF] + lane);
    float4  bv = *((const float4*)bias + lane);
    float v0 = (a0.x + a1.x + a2.x + a3.x) * rden + bf2f(rv.x) + bv.x;
    float v1 = (a0.y + a1.y + a2.y + a3.y) * rden + bf2f(rv.y) + bv.y;
    float v2 = (a0.z + a1.z + a2.z + a3.z) * rden + bf2f(rv.z) + bv.z;
    float v3 = (a0.w + a1.w + a2.w + a3.w) * rden + bf2f(rv.w) + bv.w;
    v0 = v0 > 0.f ? v0 : expm1f(v0);        // ELU(alpha=1)
    v1 = v1 > 0.f ? v1 : expm1f(v1);
    v2 = v2 > 0.f ? v2 : expm1f(v2);
    v3 = v3 > 0.f ? v3 : expm1f(v3);
    #pragma unroll
    for (int off = 16; off < 64; off <<= 1) {     // sum across the 4 heads
      v0 += __shfl_xor(v0, off);
      v1 += __shfl_xor(v1, off);
      v2 += __shfl_xor(v2, off);
      v3 += __shfl_xor(v3, off);
    }
    if (lane < 16) {                        // h2 row lives in lanes 0-15
      const float m0 = 0.25f * v0, m1 = 0.25f * v1,
                  m2 = 0.25f * v2, m3 = 0.25f * v3;
      *((float4*)&h2out[(size_t)n * FD] + lane) = make_float4(m0, m1, m2, m3);
      const float4 wwv = ((const float4*)Ww)[lane];
      float part = m0 * wwv.x + m1 * wwv.y + m2 * wwv.z + m3 * wwv.w;
      #pragma unroll
      for (int off = 1; off < 16; off <<= 1)
        part += __shfl_xor(part, off);
      if (lane == 0)
        node_w[n] = 1.f / (1.f + __expf(-(part + bw[0])));
    }
  }
}

// ---------------------------------------------------------------------------
// Fused per-graph readout + predictor: one WAVE per graph (gid sorted ->
// contiguous node range via goffs, zero atomics). Lane f streams wsum/hmax;
// gfeat staged in LDS; lanes 0-31 compute the 32 hidden units; shfl-reduce
// the final dot. Empty graphs: ws=0, mx=-inf (JAX segment semantics).
// ---------------------------------------------------------------------------
__global__ __launch_bounds__(256) void k_rp(
    const float* __restrict__ h2, const float* __restrict__ node_w,
    const int* __restrict__ goffs,
    const float* __restrict__ Wp1, const float* __restrict__ bp1,
    const float* __restrict__ Wp2, const float* __restrict__ bp2,
    float* __restrict__ out, int G)
{
  __shared__ float lws[4][FD];
  __shared__ float lmx[4][FD];
  const int w = threadIdx.x >> 6, lane = threadIdx.x & 63;
  const int g = blockIdx.x * 4 + w;

  float ws = 0.f, mx = -INFINITY;
  if (g < G) {
    const int n0 = goffs[g], n1 = goffs[g + 1];
    for (int n = n0; n < n1; ++n) {
      float v  = h2[(size_t)n * FD + lane];
      float wn = node_w[n];
      ws = fmaf(wn, v, ws);
      mx = fmaxf(mx, v);
    }
  }
  lws[w][lane] = ws;
  lmx[w][lane] = mx;
  __syncthreads();

  float acc = 0.f;
  if (g < G && lane < 32) {
    acc = bp1[lane];
    #pragma unroll 4
    for (int k = 0; k < FD; ++k)
      acc = fmaf(lws[w][k], Wp1[k * 32 + lane], acc);
    #pragma unroll 4
    for (int k = 0; k < FD; ++k)
      acc = fmaf(lmx[w][k], Wp1[(FD + k) * 32 + lane], acc);
    acc = fmaxf(acc, 0.f) * Wp2[lane];
  }
  #pragma unroll
  for (int off = 1; off < 32; off <<= 1)    // reduce lanes 0-31
    acc += __shfl_xor(acc, off);
  if (g < G && lane == 0) out[g] = acc + bp2[0];
}

// ---------------------------------------------------------------------------
extern "C" void kernel_launch(void* const* d_in, const int* in_sizes, int n_in,
                              void* d_out, int out_size, void* d_ws, size_t ws_size,
                              hipStream_t stream) {
  const float* x     = (const float*)d_in[0];
  const int*   src   = (const int*)  d_in[1];
  const int*   dst   = (const int*)  d_in[2];
  const int*   gid   = (const int*)  d_in[3];
  const float* W1    = (const float*)d_in[4];
  const float* al1   = (const float*)d_in[5];
  const float* ar1   = (const float*)d_in[6];
  const float* b1    = (const float*)d_in[7];
  const float* Wres1 = (const float*)d_in[8];
  const float* W2    = (const float*)d_in[9];
  const float* al2   = (const float*)d_in[10];
  const float* ar2   = (const float*)d_in[11];
  const float* b2    = (const float*)d_in[12];
  const float* Wres2 = (const float*)d_in[13];
  const float* Ww    = (const float*)d_in[14];
  const float* bw    = (const float*)d_in[15];
  const float* Wp1   = (const float*)d_in[16];
  const float* bp1   = (const float*)d_in[17];
  const float* Wp2   = (const float*)d_in[18];
  const float* bp2   = (const float*)d_in[19];
  float* out = (float*)d_out;

  const int N = in_sizes[3];        // gid has N elements
  const int E = in_sizes[1];        // src has E elements
  const int G = out_size;           // output is [G,1]
  const int Mpad = (N + 127) & ~127;

  // ---- workspace carve (256B-aligned) ----
  char* p = (char*)d_ws;
  auto alloc = [&](size_t bytes) {
    char* r = p;
    p += (bytes + 255) & ~(size_t)255;
    return r;
  };
  unsigned short* featbf  = (unsigned short*)alloc((size_t)Mpad * HF * 2);
  unsigned short* resbf   = (unsigned short*)alloc((size_t)Mpad * HF * 2);
  float*          el      = (float*)         alloc((size_t)N * HEADS * 4);
  float*          er      = (float*)         alloc((size_t)N * HEADS * 4);
  int*            counts  = (int*)           alloc((size_t)N * 4);
  int*            cursor  = (int*)           alloc((size_t)N * 4);
  int*            offs    = (int*)           alloc((size_t)(N + 1) * 4);
  const int nb            = (N + 1023) / 1024;
  int*            bsum    = (int*)           alloc((size_t)nb * 4);
  int*            csr_src = (int*)           alloc((size_t)E * 4);
  float*          h2      = (float*)         alloc((size_t)N * FD * 4);
  float*          node_w  = (float*)         alloc((size_t)N * 4);
  int*            goffs   = (int*)           alloc((size_t)(G + 1) * 4);
  unsigned short* xbf     = (unsigned short*)alloc((size_t)Mpad * 64 * 2);
  unsigned short* h1bf    = (unsigned short*)alloc((size_t)Mpad * HF * 2);
  unsigned short* BT1     = (unsigned short*)alloc((size_t)512 * 64 * 2);
  unsigned short* BT2     = (unsigned short*)alloc((size_t)512 * 256 * 2);
  (void)ws_size; (void)n_in;

  // ---- conversions + scratch init + goffs build (one kernel) ----
  const int n4 = N * 64 / 4;
  const int init_total = n4 + 512 * 64 + 512 * 256 + N + N + N;
  k_cvt_init<<<(init_total + 255) / 256, 256, 0, stream>>>(
      x, W1, Wres1, W2, Wres2, xbf, BT1, BT2,
      counts, cursor, gid, goffs, n4, N, G);

  // ---- CSR by destination (shared by both layers) ----
  k_hist   <<<(E + 255) / 256, 256, 0, stream>>>(dst, counts, E);
  k_scan1  <<<nb, 256, 0, stream>>>(counts, offs, bsum, N);
  k_scan2  <<<1, 64, 0, stream>>>(bsum, nb, offs, N);
  k_scan3  <<<(N + 255) / 256, 256, 0, stream>>>(offs, bsum, N);
  k_scatter<<<(E + 255) / 256, 256, 0, stream>>>(src, dst, offs, cursor, csr_src, E);

  dim3 gg(Mpad / 128, 4);

  // ---- layer 1 (flatten) ----
  gemm_mfma<64> <<<gg, 256, 0, stream>>>(xbf, BT1, al1, ar1,
                                         featbf, resbf, el, er, N);
  agg_l1        <<<N, 256, 0, stream>>>(featbf, resbf, el, er, b1, csr_src,
                                        offs, h1bf);

  // ---- layer 2 (mean) ----
  gemm_mfma<256><<<gg, 256, 0, stream>>>(h1bf, BT2, al2, ar2,
                                         featbf, resbf, el, er, N);
  agg_l2        <<<N, 256, 0, stream>>>(featbf, resbf, el, er, b2, csr_src,
                                        offs, Ww, bw, h2, node_w);

  // ---- fused per-graph readout + predictor (no atomics) ----
  k_rp<<<(G + 3) / 4, 256, 0, stream>>>(h2, node_w, goffs,
                                        Wp1, bp1, Wp2, bp2, out, G);
}